// Round 1
// baseline (4509.141 us; speedup 1.0000x reference)
//
#include <hip/hip_runtime.h>
#include <math.h>

constexpr int C_B = 2, C_S = 1024, C_D = 512, C_H = 8, C_DH = 64,
              C_F = 2048, C_L = 6, C_V = 32000;
constexpr float C_EPS = 1e-6f;

using bf16x8 = __attribute__((ext_vector_type(8))) __bf16;
using f32x4  = __attribute__((ext_vector_type(4))) float;

__device__ __forceinline__ f32x4 mfma16(bf16x8 a, bf16x8 b, f32x4 c) {
  return __builtin_amdgcn_mfma_f32_16x16x32_bf16(a, b, c, 0, 0, 0);
}

__device__ __forceinline__ float block_sum(float v, float* sbuf) {
#pragma unroll
  for (int o = 32; o > 0; o >>= 1) v += __shfl_down(v, o);
  __syncthreads();
  if ((threadIdx.x & 63) == 0) sbuf[threadIdx.x >> 6] = v;
  __syncthreads();
  return (sbuf[0] + sbuf[1]) + (sbuf[2] + sbuf[3]);
}

__device__ __forceinline__ float block_max(float v, float* sbuf) {
#pragma unroll
  for (int o = 32; o > 0; o >>= 1) v = fmaxf(v, __shfl_down(v, o));
  __syncthreads();
  if ((threadIdx.x & 63) == 0) sbuf[threadIdx.x >> 6] = v;
  __syncthreads();
  return fmaxf(fmaxf(sbuf[0], sbuf[1]), fmaxf(sbuf[2], sbuf[3]));
}

// ---------------------------------------------------------------------------
// Generic batched GEMM: C[M,N] (+)= scale * (A[M,K] @ B) + bias, optional relu.
// B_NK=false: B stored row-major [K][N] (weights, V-matrix).
// B_NK=true : B stored row-major [N][K] (i.e. B^T given; used for Q@K^T).
// Batch z decomposed as (zb, zh) = (z/hdim, z%hdim); per-operand offsets
// off = zb*s?b + zh*s?h. Requires M%64==0, N%64==0, K%32==0.
// Tile 64x64, 4 waves, each wave 2x2 tiles of 16x16, mfma_f32_16x16x32_bf16.
// ---------------------------------------------------------------------------
template <bool B_NK, bool BIAS, bool RELU, bool RESID>
__global__ __launch_bounds__(256) void gemm_kernel(
    const float* __restrict__ A, int lda, long sAb, long sAh,
    const float* __restrict__ Bm, int ldb, long sBb, long sBh,
    float* __restrict__ C, int ldc, long sCb, long sCh,
    const float* __restrict__ bias, int K, int hdim, float scale) {
  __shared__ __bf16 As[64][40];  // [m][k], pad 40 to break b128 bank aliasing
  __shared__ __bf16 Bs[64][40];  // [n][k] (B transposed in LDS)

  const int z = blockIdx.z;
  const int zb = z / hdim;
  const int zh = z - zb * hdim;
  const float* Ap = A + zb * sAb + zh * sAh;
  const float* Bp = Bm + zb * sBb + zh * sBh;
  float* Cp = C + zb * sCb + zh * sCh;

  const int m0 = blockIdx.y * 64;
  const int n0 = blockIdx.x * 64;
  const int t = threadIdx.x;
  const int lane = t & 63;
  const int wid = t >> 6;
  const int wm = (wid >> 1) * 32;
  const int wn = (wid & 1) * 32;
  const int sr = t >> 2;        // staging row 0..63
  const int sk = (t & 3) * 8;   // staging k seg {0,8,16,24}
  const int fr = lane & 15;     // fragment row/col
  const int fk = (lane >> 4) * 8;

  f32x4 acc00 = {0.f, 0.f, 0.f, 0.f};
  f32x4 acc01 = {0.f, 0.f, 0.f, 0.f};
  f32x4 acc10 = {0.f, 0.f, 0.f, 0.f};
  f32x4 acc11 = {0.f, 0.f, 0.f, 0.f};

  for (int k0 = 0; k0 < K; k0 += 32) {
    {  // stage A: [m][k]
      const float* ap = Ap + (long)(m0 + sr) * lda + (k0 + sk);
      float4 u = *(const float4*)ap;
      float4 w = *(const float4*)(ap + 4);
      bf16x8 pk;
      pk[0] = (__bf16)u.x; pk[1] = (__bf16)u.y; pk[2] = (__bf16)u.z; pk[3] = (__bf16)u.w;
      pk[4] = (__bf16)w.x; pk[5] = (__bf16)w.y; pk[6] = (__bf16)w.z; pk[7] = (__bf16)w.w;
      *(bf16x8*)(&As[sr][sk]) = pk;
    }
    if (B_NK) {  // B given as [N][K]: direct copy
      const float* bp = Bp + (long)(n0 + sr) * ldb + (k0 + sk);
      float4 u = *(const float4*)bp;
      float4 w = *(const float4*)(bp + 4);
      bf16x8 pk;
      pk[0] = (__bf16)u.x; pk[1] = (__bf16)u.y; pk[2] = (__bf16)u.z; pk[3] = (__bf16)u.w;
      pk[4] = (__bf16)w.x; pk[5] = (__bf16)w.y; pk[6] = (__bf16)w.z; pk[7] = (__bf16)w.w;
      *(bf16x8*)(&Bs[sr][sk]) = pk;
    } else {  // B given as [K][N]: transpose into LDS.
      // thread t: k = t>>3, n = (t&7) + 8j  -> scalar LDS stores conflict-free
      const int bk = t >> 3;
      const int bn2 = t & 7;
      const float* bp = Bp + (long)(k0 + bk) * ldb + (n0 + bn2);
#pragma unroll
      for (int j = 0; j < 8; ++j) Bs[bn2 + 8 * j][bk] = (__bf16)bp[8 * j];
    }
    __syncthreads();
    bf16x8 a0 = *(const bf16x8*)(&As[wm + fr][fk]);
    bf16x8 a1 = *(const bf16x8*)(&As[wm + 16 + fr][fk]);
    bf16x8 b0 = *(const bf16x8*)(&Bs[wn + fr][fk]);
    bf16x8 b1 = *(const bf16x8*)(&Bs[wn + 16 + fr][fk]);
    acc00 = mfma16(a0, b0, acc00);
    acc01 = mfma16(a0, b1, acc01);
    acc10 = mfma16(a1, b0, acc10);
    acc11 = mfma16(a1, b1, acc11);
    __syncthreads();
  }

  // epilogue: C/D layout row=(lane>>4)*4+reg, col=lane&15
  const int col0 = lane & 15;
  const int row0 = (lane >> 4) * 4;
  f32x4 accs[2][2] = {{acc00, acc01}, {acc10, acc11}};
#pragma unroll
  for (int tm = 0; tm < 2; ++tm) {
#pragma unroll
    for (int tn = 0; tn < 2; ++tn) {
      const int colg = n0 + wn + 16 * tn + col0;
      const float bv = BIAS ? bias[colg] : 0.0f;
#pragma unroll
      for (int r = 0; r < 4; ++r) {
        const int rowg = m0 + wm + 16 * tm + row0 + r;
        float v = accs[tm][tn][r] * scale + bv;
        if (RELU) v = fmaxf(v, 0.0f);
        const long ci = (long)rowg * ldc + colg;
        if (RESID) Cp[ci] += v; else Cp[ci] = v;
      }
    }
  }
}

// ---------------------------------------------------------------------------
// embedding * sqrt(D) + positional encoding (computed inline)
// ---------------------------------------------------------------------------
__global__ __launch_bounds__(256) void embed_kernel(
    const int* __restrict__ tok, const float* __restrict__ emb,
    float* __restrict__ out) {
  const int bs = blockIdx.x;              // 0..B*S-1
  const int spos = bs & (C_S - 1);
  const int tk = tok[bs];
  const float* ep = emb + (long)tk * C_D;
  float* op = out + (long)bs * C_D;
  for (int d = threadIdx.x; d < C_D; d += 256) {
    const int i2 = d & ~1;
    const float freq = __expf((float)i2 * (-9.210340371976184f / 512.0f));
    const float ang = (float)spos * freq;
    const float pe = (d & 1) ? cosf(ang) : sinf(ang);
    op[d] = ep[d] * 22.62741699796952f + pe;
  }
}

// ---------------------------------------------------------------------------
// LayerNorm: (x - mean) / (std_ddof1 + eps), D=512, one block per row
// ---------------------------------------------------------------------------
__global__ __launch_bounds__(256) void ln_kernel(const float* __restrict__ x,
                                                 float* __restrict__ out) {
  __shared__ float sbuf[4];
  const long row = blockIdx.x;
  const float* xp = x + row * C_D;
  float* op = out + row * C_D;
  const int t = threadIdx.x;
  const float v0 = xp[t];
  const float v1 = xp[t + 256];
  const float mean = block_sum(v0 + v1, sbuf) * (1.0f / 512.0f);
  const float d0 = v0 - mean, d1 = v1 - mean;
  const float ss = block_sum(d0 * d0 + d1 * d1, sbuf);
  const float stdv = sqrtf(ss * (1.0f / 511.0f));
  const float inv = 1.0f / (stdv + C_EPS);
  op[t] = d0 * inv;
  op[t + 256] = d1 * inv;
}

// ---------------------------------------------------------------------------
// Masked softmax over rows of length S=1024. MODE 0: mask[b*S + col]
// (src_mask [B,1,1,S]); MODE 1: mask[b*S*S + q*S + col] (tgt_mask [B,1,S,S]).
// ---------------------------------------------------------------------------
template <int MODE>
__global__ __launch_bounds__(256) void softmax_kernel(
    float* __restrict__ sc, const int* __restrict__ mask) {
  __shared__ float sbuf[4];
  const int row = blockIdx.x;            // (b*H + h)*S + q
  const int b = row >> 13;               // / (H*S)
  const int qpos = row & (C_S - 1);
  float* p = sc + (long)row * C_S;
  const int t = threadIdx.x;
  float v[4];
#pragma unroll
  for (int j = 0; j < 4; ++j) {
    const int col = t + j * 256;
    const float xv = p[col];
    const int mk = (MODE == 0) ? mask[b * C_S + col]
                               : mask[((long)b * C_S + qpos) * C_S + col];
    v[j] = (mk == 0) ? -1e9f : xv;
  }
  float mx = fmaxf(fmaxf(v[0], v[1]), fmaxf(v[2], v[3]));
  mx = block_max(mx, sbuf);
  float e[4];
  float s = 0.f;
#pragma unroll
  for (int j = 0; j < 4; ++j) { e[j] = __expf(v[j] - mx); s += e[j]; }
  s = block_sum(s, sbuf);
  const float inv = 1.0f / s;
#pragma unroll
  for (int j = 0; j < 4; ++j) p[t + j * 256] = e[j] * inv;
}

// ---------------------------------------------------------------------------
// In-place log_softmax over rows of length V=32000 (3 passes)
// ---------------------------------------------------------------------------
__global__ __launch_bounds__(256) void logsoftmax_kernel(float* __restrict__ out) {
  __shared__ float sbuf[4];
  const long row = blockIdx.x;
  float* p = out + row * C_V;
  const int t = threadIdx.x;
  float mx = -1e30f;
  for (int i = t; i < C_V; i += 256) mx = fmaxf(mx, p[i]);
  mx = block_max(mx, sbuf);
  float s = 0.f;
  for (int i = t; i < C_V; i += 256) s += __expf(p[i] - mx);
  s = block_sum(s, sbuf);
  const float lz = mx + logf(s);
  for (int i = t; i < C_V; i += 256) p[i] -= lz;
}

// ---------------------------------------------------------------------------
// host-side helpers
// ---------------------------------------------------------------------------
static void run_gemm(hipStream_t st, int mode,
                     const float* A, int lda, long sAb, long sAh,
                     const float* B, int ldb, long sBb, long sBh,
                     float* C, int ldc, long sCb, long sCh,
                     const float* bias, int M, int N, int K, int batch,
                     int hdim, float scale) {
  dim3 g(N / 64, M / 64, batch), blk(256, 1, 1);
  switch (mode) {
    case 0:  // KN, bias
      gemm_kernel<false, true, false, false><<<g, blk, 0, st>>>(
          A, lda, sAb, sAh, B, ldb, sBb, sBh, C, ldc, sCb, sCh, bias, K, hdim, scale);
      break;
    case 1:  // KN, bias, relu
      gemm_kernel<false, true, true, false><<<g, blk, 0, st>>>(
          A, lda, sAb, sAh, B, ldb, sBb, sBh, C, ldc, sCb, sCh, bias, K, hdim, scale);
      break;
    case 2:  // KN, bias, residual-accumulate
      gemm_kernel<false, true, false, true><<<g, blk, 0, st>>>(
          A, lda, sAb, sAh, B, ldb, sBb, sBh, C, ldc, sCb, sCh, bias, K, hdim, scale);
      break;
    case 3:  // NK (B^T given), no bias (scores)
      gemm_kernel<true, false, false, false><<<g, blk, 0, st>>>(
          A, lda, sAb, sAh, B, ldb, sBb, sBh, C, ldc, sCb, sCh, bias, K, hdim, scale);
      break;
    case 4:  // KN, no bias (attn @ V)
      gemm_kernel<false, false, false, false><<<g, blk, 0, st>>>(
          A, lda, sAb, sAh, B, ldb, sBb, sBh, C, ldc, sCb, sCh, bias, K, hdim, scale);
      break;
  }
}

static void run_attention(hipStream_t st, const float* hq, const float* hkv,
                          const float* wq, const float* bq, const float* wk,
                          const float* bk, const float* wv, const float* bv,
                          const float* wo, const float* bo, const int* mask,
                          int maskMode, float* xres, float* qb, float* kb,
                          float* vb, float* ob, float* scb) {
  const long sBSD = (long)C_S * C_D;
  const long sSS = (long)C_S * C_S;
  const int rows = C_B * C_S;
  // Q,K,V projections
  run_gemm(st, 0, hq, C_D, 0, 0, wq, C_D, 0, 0, qb, C_D, 0, 0, bq, rows, C_D, C_D, 1, 1, 1.f);
  run_gemm(st, 0, hkv, C_D, 0, 0, wk, C_D, 0, 0, kb, C_D, 0, 0, bk, rows, C_D, C_D, 1, 1, 1.f);
  run_gemm(st, 0, hkv, C_D, 0, 0, wv, C_D, 0, 0, vb, C_D, 0, 0, bv, rows, C_D, C_D, 1, 1, 1.f);
  // scores = Q @ K^T / sqrt(DH); batched over (b,h)
  run_gemm(st, 3, qb, C_D, sBSD, C_DH, kb, C_D, sBSD, C_DH, scb, C_S,
           (long)C_H * sSS, sSS, nullptr, C_S, C_S, C_DH, C_B * C_H, C_H, 0.125f);
  if (maskMode == 0)
    softmax_kernel<0><<<C_B * C_H * C_S, 256, 0, st>>>(scb, mask);
  else
    softmax_kernel<1><<<C_B * C_H * C_S, 256, 0, st>>>(scb, mask);
  // O = P @ V
  run_gemm(st, 4, scb, C_S, (long)C_H * sSS, sSS, vb, C_D, sBSD, C_DH, ob, C_D,
           sBSD, C_DH, nullptr, C_S, C_DH, C_S, C_B * C_H, C_H, 1.f);
  // x += O @ Wo + bo
  run_gemm(st, 2, ob, C_D, 0, 0, wo, C_D, 0, 0, xres, C_D, 0, 0, bo, rows, C_D, C_D, 1, 1, 1.f);
}

static void run_ffn(hipStream_t st, const float* h, const float* w1,
                    const float* b1, const float* w2, const float* b2,
                    float* xres, float* mid) {
  const int rows = C_B * C_S;
  run_gemm(st, 1, h, C_D, 0, 0, w1, C_F, 0, 0, mid, C_F, 0, 0, b1, rows, C_F, C_D, 1, 1, 1.f);
  run_gemm(st, 2, mid, C_F, 0, 0, w2, C_D, 0, 0, xres, C_D, 0, 0, b2, rows, C_D, C_F, 1, 1, 1.f);
}

extern "C" void kernel_launch(void* const* d_in, const int* in_sizes, int n_in,
                              void* d_out, int out_size, void* d_ws,
                              size_t ws_size, hipStream_t stream) {
  (void)in_sizes; (void)n_in; (void)out_size; (void)ws_size;
  const int* src = (const int*)d_in[0];
  const int* tgt = (const int*)d_in[1];
  const int* src_mask = (const int*)d_in[2];
  const int* tgt_mask = (const int*)d_in[3];
  const float* src_emb = (const float*)d_in[4];
  const float* tgt_emb = (const float*)d_in[5];
  const float* enc_wq = (const float*)d_in[6];
  const float* enc_bq = (const float*)d_in[7];
  const float* enc_wk = (const float*)d_in[8];
  const float* enc_bk = (const float*)d_in[9];
  const float* enc_wv = (const float*)d_in[10];
  const float* enc_bv = (const float*)d_in[11];
  const float* enc_wo = (const float*)d_in[12];
  const float* enc_bo = (const float*)d_in[13];
  const float* enc_w1 = (const float*)d_in[14];
  const float* enc_b1 = (const float*)d_in[15];
  const float* enc_w2 = (const float*)d_in[16];
  const float* enc_b2 = (const float*)d_in[17];
  const float* dsa_wq = (const float*)d_in[18];
  const float* dsa_bq = (const float*)d_in[19];
  const float* dsa_wk = (const float*)d_in[20];
  const float* dsa_bk = (const float*)d_in[21];
  const float* dsa_wv = (const float*)d_in[22];
  const float* dsa_bv = (const float*)d_in[23];
  const float* dsa_wo = (const float*)d_in[24];
  const float* dsa_bo = (const float*)d_in[25];
  const float* dca_wq = (const float*)d_in[26];
  const float* dca_bq = (const float*)d_in[27];
  const float* dca_wk = (const float*)d_in[28];
  const float* dca_bk = (const float*)d_in[29];
  const float* dca_wv = (const float*)d_in[30];
  const float* dca_bv = (const float*)d_in[31];
  const float* dca_wo = (const float*)d_in[32];
  const float* dca_bo = (const float*)d_in[33];
  const float* dec_w1 = (const float*)d_in[34];
  const float* dec_b1 = (const float*)d_in[35];
  const float* dec_w2 = (const float*)d_in[36];
  const float* dec_b2 = (const float*)d_in[37];
  const float* proj_w = (const float*)d_in[38];
  const float* proj_b = (const float*)d_in[39];
  float* out = (float*)d_out;

  // workspace layout (floats)
  float* ws = (float*)d_ws;
  const long nBSD = (long)C_B * C_S * C_D;  // 1,048,576
  float* x = ws;                 // residual stream (enc, then reused for dec)
  float* h = x + nBSD;           // layernorm output
  float* qb = h + nBSD;
  float* kb = qb + nBSD;
  float* vb = kb + nBSD;
  float* ob = vb + nBSD;
  float* encb = ob + nBSD;       // encoder output
  float* mid = encb + nBSD;                    // B*S*F
  float* scb = mid + (long)C_B * C_S * C_F;    // B*H*S*S

  const int rows = C_B * C_S;
  const long oDD = (long)C_D * C_D, oDF = (long)C_D * C_F;

  // ---- encoder ----
  embed_kernel<<<rows, 256, 0, stream>>>(src, src_emb, x);
  for (int i = 0; i < C_L; ++i) {
    const long oW = i * oDD, oB = (long)i * C_D;
    ln_kernel<<<rows, 256, 0, stream>>>(x, h);
    run_attention(stream, h, h, enc_wq + oW, enc_bq + oB, enc_wk + oW,
                  enc_bk + oB, enc_wv + oW, enc_bv + oB, enc_wo + oW,
                  enc_bo + oB, src_mask, 0, x, qb, kb, vb, ob, scb);
    ln_kernel<<<rows, 256, 0, stream>>>(x, h);
    run_ffn(stream, h, enc_w1 + i * oDF, enc_b1 + (long)i * C_F,
            enc_w2 + i * oDF, enc_b2 + oB, x, mid);
  }
  ln_kernel<<<rows, 256, 0, stream>>>(x, encb);

  // ---- decoder (x reused as decoder stream) ----
  embed_kernel<<<rows, 256, 0, stream>>>(tgt, tgt_emb, x);
  for (int i = 0; i < C_L; ++i) {
    const long oW = i * oDD, oB = (long)i * C_D;
    // self-attn (reference uses src_mask here)
    ln_kernel<<<rows, 256, 0, stream>>>(x, h);
    run_attention(stream, h, h, dsa_wq + oW, dsa_bq + oB, dsa_wk + oW,
                  dsa_bk + oB, dsa_wv + oW, dsa_bv + oB, dsa_wo + oW,
                  dsa_bo + oB, src_mask, 0, x, qb, kb, vb, ob, scb);
    // cross-attn (reference uses tgt_mask here)
    ln_kernel<<<rows, 256, 0, stream>>>(x, h);
    run_attention(stream, h, encb, dca_wq + oW, dca_bq + oB, dca_wk + oW,
                  dca_bk + oB, dca_wv + oW, dca_bv + oB, dca_wo + oW,
                  dca_bo + oB, tgt_mask, 1, x, qb, kb, vb, ob, scb);
    ln_kernel<<<rows, 256, 0, stream>>>(x, h);
    run_ffn(stream, h, dec_w1 + i * oDF, dec_b1 + (long)i * C_F,
            dec_w2 + i * oDF, dec_b2 + oB, x, mid);
  }
  ln_kernel<<<rows, 256, 0, stream>>>(x, h);

  // ---- final projection + log_softmax ----
  run_gemm(stream, 0, h, C_D, 0, 0, proj_w, C_V, 0, 0, out, C_V, 0, 0, proj_b,
           rows, C_V, C_D, 1, 1, 1.f);
  logsoftmax_kernel<<<rows, 256, 0, stream>>>(out);
}

// Round 2
// 2937.727 us; speedup vs baseline: 1.5349x; 1.5349x over previous
//
#include <hip/hip_runtime.h>
#include <math.h>

constexpr int C_B = 2, C_S = 1024, C_D = 512, C_H = 8, C_DH = 64,
              C_F = 2048, C_L = 6, C_V = 32000;
constexpr float C_EPS = 1e-6f;

using bf16x8 = __attribute__((ext_vector_type(8))) __bf16;
using bf16x4v = __attribute__((ext_vector_type(4))) __bf16;
using f32x4  = __attribute__((ext_vector_type(4))) float;

__device__ __forceinline__ f32x4 mfma16(bf16x8 a, bf16x8 b, f32x4 c) {
  return __builtin_amdgcn_mfma_f32_16x16x32_bf16(a, b, c, 0, 0, 0);
}

__device__ __forceinline__ void async16(const __bf16* g, __bf16* l) {
  __builtin_amdgcn_global_load_lds(
      (const __attribute__((address_space(1))) void*)g,
      (__attribute__((address_space(3))) void*)l, 16, 0, 0);
}

__device__ __forceinline__ float block_sum(float v, float* sbuf) {
#pragma unroll
  for (int o = 32; o > 0; o >>= 1) v += __shfl_down(v, o);
  __syncthreads();
  if ((threadIdx.x & 63) == 0) sbuf[threadIdx.x >> 6] = v;
  __syncthreads();
  return (sbuf[0] + sbuf[1]) + (sbuf[2] + sbuf[3]);
}

__device__ __forceinline__ float block_max(float v, float* sbuf) {
#pragma unroll
  for (int o = 32; o > 0; o >>= 1) v = fmaxf(v, __shfl_down(v, o));
  __syncthreads();
  if ((threadIdx.x & 63) == 0) sbuf[threadIdx.x >> 6] = v;
  __syncthreads();
  return fmaxf(fmaxf(sbuf[0], sbuf[1]), fmaxf(sbuf[2], sbuf[3]));
}

// ---------------------------------------------------------------------------
// bf16 GEMM, B in [N][K] layout. C[M,N] = scale*(A@B^T) + bias, epilogues:
// EPI 0: store bf16; 1: store bf16+relu; 3: store f32; 4: f32 atomicAdd
// (residual, bias only when zb==0; z = K-split index via sAb/sBb k-offsets).
// TRI: bias segmented per 512 cols (b0/b1/b2). SWAP: m from blockIdx.x.
// global_load_lds staging (16B/lane), XOR granule swizzle in LDS.
// ---------------------------------------------------------------------------
template <int BM, int BN, int EPI, bool TRI, bool SWAP>
__global__ __launch_bounds__(256) void gemm_bt(
    const __bf16* __restrict__ A, int lda, long sAb, long sAh,
    const __bf16* __restrict__ B, int ldb, long sBb, long sBh,
    void* __restrict__ Cv, int ldc, long sCb, long sCh,
    const float* __restrict__ b0, const float* __restrict__ b1,
    const float* __restrict__ b2, int K, int hdim, float scale) {
  constexpr int BK = 32;
  __shared__ __bf16 As[BM][BK];
  __shared__ __bf16 Bs[BN][BK];
  const int z = blockIdx.z;
  const int zb = z / hdim, zh = z - zb * hdim;
  const __bf16* Ap = A + (long)zb * sAb + (long)zh * sAh;
  const __bf16* Bp = B + (long)zb * sBb + (long)zh * sBh;
  const int m0 = (SWAP ? blockIdx.x : blockIdx.y) * BM;
  const int n0 = (SWAP ? blockIdx.y : blockIdx.x) * BN;
  const int t = threadIdx.x, lane = t & 63, w = t >> 6;
  const int wr = w >> 1, wc = w & 1;
  constexpr int WM = BM / 2, WN = BN / 2, TM = WM / 16, TN = WN / 16;
  constexpr int AI = BM / 64, BI = BN / 64;
  const int srow = lane >> 2;       // row within 16-row staging group
  const int sg = lane & 3;          // LDS granule this lane fills
  const int fr = lane & 15, fq = lane >> 4;

  f32x4 acc[TM][TN] = {};
  for (int k0 = 0; k0 < K; k0 += BK) {
#pragma unroll
    for (int j = 0; j < AI; ++j) {
      const int r0 = w * (AI * 16) + j * 16;
      const int row = r0 + srow;
      const int s = sg ^ ((row >> 1) & 3);  // global k-seg for this granule
      async16(Ap + (long)(m0 + row) * lda + (k0 + s * 8), &As[r0][0]);
    }
#pragma unroll
    for (int j = 0; j < BI; ++j) {
      const int r0 = w * (BI * 16) + j * 16;
      const int row = r0 + srow;
      const int s = sg ^ ((row >> 1) & 3);
      async16(Bp + (long)(n0 + row) * ldb + (k0 + s * 8), &Bs[r0][0]);
    }
    __syncthreads();
    bf16x8 af[TM], bfr[TN];
#pragma unroll
    for (int i = 0; i < TM; ++i) {
      const int row = wr * WM + i * 16 + fr;
      const int g = fq ^ ((row >> 1) & 3);
      af[i] = *(const bf16x8*)&As[row][g * 8];
    }
#pragma unroll
    for (int i = 0; i < TN; ++i) {
      const int row = wc * WN + i * 16 + fr;
      const int g = fq ^ ((row >> 1) & 3);
      bfr[i] = *(const bf16x8*)&Bs[row][g * 8];
    }
#pragma unroll
    for (int i = 0; i < TM; ++i)
#pragma unroll
      for (int j = 0; j < TN; ++j) acc[i][j] = mfma16(af[i], bfr[j], acc[i][j]);
    __syncthreads();
  }

  const long co = (long)zb * sCb + (long)zh * sCh;
  const int rq = (lane >> 4) * 4;
#pragma unroll
  for (int i = 0; i < TM; ++i) {
#pragma unroll
    for (int j = 0; j < TN; ++j) {
      const int colg = n0 + wc * WN + j * 16 + fr;
      float bv = 0.f;
      if (b0) {
        if (TRI) {
          const float* bp = colg < 512 ? b0 : (colg < 1024 ? b1 : b2);
          bv = bp[colg & 511];
        } else {
          bv = b0[colg];
        }
      }
      if (EPI == 4 && zb != 0) bv = 0.f;
#pragma unroll
      for (int r = 0; r < 4; ++r) {
        const int rowg = m0 + wr * WM + i * 16 + rq + r;
        const long ci = co + (long)rowg * ldc + colg;
        float v = acc[i][j][r] * scale + bv;
        if (EPI == 0) ((__bf16*)Cv)[ci] = (__bf16)v;
        else if (EPI == 1) ((__bf16*)Cv)[ci] = (__bf16)fmaxf(v, 0.f);
        else if (EPI == 3) ((float*)Cv)[ci] = v;
        else atomicAdd((float*)Cv + ci, v);
      }
    }
  }
}

// ---------------------------------------------------------------------------
// transpose + f32->bf16: in [z][R][C] f32 -> out [z][C][R] bf16 (+outOff)
// ---------------------------------------------------------------------------
__global__ __launch_bounds__(256) void transpose_cvt(
    const float* __restrict__ in, __bf16* __restrict__ out, int R, int C,
    long inS, long outS, long outOff) {
  __shared__ __bf16 tile[32][33];
  in += (long)blockIdx.z * inS;
  out += (long)blockIdx.z * outS + outOff;
  const int c0 = blockIdx.x * 32, r0 = blockIdx.y * 32;
  const int tc = threadIdx.x & 31, tr = threadIdx.x >> 5;  // 8 rows/pass
#pragma unroll
  for (int j = 0; j < 32; j += 8)
    tile[tr + j][tc] = (__bf16)in[(long)(r0 + tr + j) * C + (c0 + tc)];
  __syncthreads();
#pragma unroll
  for (int j = 0; j < 32; j += 8)
    out[(long)(c0 + tr + j) * R + (r0 + tc)] = tile[tc][tr + j];
}

// ---------------------------------------------------------------------------
// V transpose: qkv[b*S+s][1024 + h*64 + dh] -> vT[(b*8+h)*64 + dh][s]
// ---------------------------------------------------------------------------
__global__ __launch_bounds__(256) void vtrans_kernel(
    const __bf16* __restrict__ qkv, __bf16* __restrict__ vT) {
  __shared__ __bf16 tile[32][33];
  const int z = blockIdx.z, b = z >> 3, h = z & 7;
  const int s0 = blockIdx.x * 32, d0 = blockIdx.y * 32;
  const int tc = threadIdx.x & 31, tr = threadIdx.x >> 5;
  const __bf16* src = qkv + (long)(b << 10) * 1536 + 1024 + h * 64;
#pragma unroll
  for (int j = 0; j < 32; j += 8)
    tile[tr + j][tc] = src[(long)(s0 + tr + j) * 1536 + (d0 + tc)];
  __syncthreads();
  __bf16* dst = vT + (long)z * 64 * 1024;
#pragma unroll
  for (int j = 0; j < 32; j += 8)
    dst[(long)(d0 + tr + j) * 1024 + (s0 + tc)] = tile[tc][tr + j];
}

// ---------------------------------------------------------------------------
__global__ __launch_bounds__(256) void embed_kernel(
    const int* __restrict__ tok, const float* __restrict__ emb,
    float* __restrict__ out) {
  const int bs = blockIdx.x;
  const int spos = bs & (C_S - 1);
  const int tk = tok[bs];
  const float* ep = emb + (long)tk * C_D;
  float* op = out + (long)bs * C_D;
  for (int d = threadIdx.x; d < C_D; d += 256) {
    const int i2 = d & ~1;
    const float freq = __expf((float)i2 * (-9.210340371976184f / 512.0f));
    const float ang = (float)spos * freq;
    const float pe = (d & 1) ? cosf(ang) : sinf(ang);
    op[d] = ep[d] * 22.62741699796952f + pe;
  }
}

__global__ __launch_bounds__(256) void ln_kernel(const float* __restrict__ x,
                                                 __bf16* __restrict__ out) {
  __shared__ float sbuf[4];
  const long row = blockIdx.x;
  const float* xp = x + row * C_D;
  __bf16* op = out + row * C_D;
  const int t = threadIdx.x;
  const float v0 = xp[t];
  const float v1 = xp[t + 256];
  const float mean = block_sum(v0 + v1, sbuf) * (1.0f / 512.0f);
  const float d0 = v0 - mean, d1 = v1 - mean;
  const float ss = block_sum(d0 * d0 + d1 * d1, sbuf);
  const float stdv = sqrtf(ss * (1.0f / 511.0f));
  const float inv = 1.0f / (stdv + C_EPS);
  op[t] = (__bf16)(d0 * inv);
  op[t + 256] = (__bf16)(d1 * inv);
}

// masked softmax over bf16 rows of length S=1024 (in-place)
template <int MODE>
__global__ __launch_bounds__(256) void softmax_kernel(
    __bf16* __restrict__ sc, const int* __restrict__ mask) {
  __shared__ float sbuf[4];
  const int row = blockIdx.x;  // (b*H+h)*S + q
  const int b = row >> 13;
  const int qpos = row & (C_S - 1);
  __bf16* p = sc + (long)row * C_S;
  const int t = threadIdx.x;
  const bf16x4v pv = *(const bf16x4v*)(p + t * 4);
  const int4 mk = (MODE == 0)
      ? *(const int4*)(mask + b * C_S + t * 4)
      : *(const int4*)(mask + ((long)b * C_S + qpos) * C_S + t * 4);
  float v[4];
  v[0] = mk.x == 0 ? -1e9f : (float)pv[0];
  v[1] = mk.y == 0 ? -1e9f : (float)pv[1];
  v[2] = mk.z == 0 ? -1e9f : (float)pv[2];
  v[3] = mk.w == 0 ? -1e9f : (float)pv[3];
  float mx = fmaxf(fmaxf(v[0], v[1]), fmaxf(v[2], v[3]));
  mx = block_max(mx, sbuf);
  float e[4], s = 0.f;
#pragma unroll
  for (int j = 0; j < 4; ++j) { e[j] = __expf(v[j] - mx); s += e[j]; }
  s = block_sum(s, sbuf);
  const float inv = 1.0f / s;
  bf16x4v o;
#pragma unroll
  for (int j = 0; j < 4; ++j) o[j] = (__bf16)(e[j] * inv);
  *(bf16x4v*)(p + t * 4) = o;
}

// 2-pass online log_softmax, rows of V=32000 f32, in-place
__global__ __launch_bounds__(256) void logsoftmax_kernel(float* __restrict__ out) {
  __shared__ float sm[4], sl[4];
  const long row = blockIdx.x;
  float* p = out + row * C_V;
  const int t = threadIdx.x, lane = t & 63, w = t >> 6;
  float m = -1e30f, l = 0.f;
  for (int i = t; i < C_V; i += 256) {
    const float v = p[i];
    const float mn = fmaxf(m, v);
    l = l * __expf(m - mn) + __expf(v - mn);
    m = mn;
  }
#pragma unroll
  for (int o = 32; o > 0; o >>= 1) {
    const float m2 = __shfl_down(m, o), l2 = __shfl_down(l, o);
    const float M = fmaxf(m, m2);
    l = l * __expf(m - M) + l2 * __expf(m2 - M);
    m = M;
  }
  if (lane == 0) { sm[w] = m; sl[w] = l; }
  __syncthreads();
  const float M = fmaxf(fmaxf(sm[0], sm[1]), fmaxf(sm[2], sm[3]));
  const float L = sl[0] * __expf(sm[0] - M) + sl[1] * __expf(sm[1] - M) +
                  sl[2] * __expf(sm[2] - M) + sl[3] * __expf(sm[3] - M);
  const float lz = M + logf(L);
  for (int i = t; i < C_V; i += 256) p[i] -= lz;
}

// ---------------------------------------------------------------------------
extern "C" void kernel_launch(void* const* d_in, const int* in_sizes, int n_in,
                              void* d_out, int out_size, void* d_ws,
                              size_t ws_size, hipStream_t stream) {
  (void)in_sizes; (void)n_in; (void)out_size; (void)ws_size;
  const int* src = (const int*)d_in[0];
  const int* tgt = (const int*)d_in[1];
  const int* src_mask = (const int*)d_in[2];
  const int* tgt_mask = (const int*)d_in[3];
  const float* src_emb = (const float*)d_in[4];
  const float* tgt_emb = (const float*)d_in[5];
  const float* in_f[40];
  for (int i = 0; i < 40; ++i) in_f[i] = (const float*)d_in[i];
  float* out = (float*)d_out;

  // ---- workspace carve-up ----
  char* wp = (char*)d_ws;
  auto alloc = [&](size_t bytes) -> char* {
    char* r = wp; wp += (bytes + 255) & ~(size_t)255; return r;
  };
  const long eQKV = (long)6 * 1536 * 512, eDD = (long)6 * 512 * 512,
             eDF = (long)6 * 2048 * 512;
  __bf16* encQKV = (__bf16*)alloc(eQKV * 2);
  __bf16* dsaQKV = (__bf16*)alloc(eQKV * 2);
  __bf16* dcaQKV = (__bf16*)alloc(eQKV * 2);
  __bf16* encWoT = (__bf16*)alloc(eDD * 2);
  __bf16* dsaWoT = (__bf16*)alloc(eDD * 2);
  __bf16* dcaWoT = (__bf16*)alloc(eDD * 2);
  __bf16* encW1T = (__bf16*)alloc(eDF * 2);
  __bf16* encW2T = (__bf16*)alloc(eDF * 2);
  __bf16* decW1T = (__bf16*)alloc(eDF * 2);
  __bf16* decW2T = (__bf16*)alloc(eDF * 2);
  __bf16* projT  = (__bf16*)alloc((long)32000 * 512 * 2);
  float*  x      = (float*)alloc((long)2048 * 512 * 4);
  __bf16* h      = (__bf16*)alloc((long)2048 * 512 * 2);
  __bf16* encb   = (__bf16*)alloc((long)2048 * 512 * 2);
  __bf16* qkv    = (__bf16*)alloc((long)2048 * 1536 * 2);
  __bf16* vT     = (__bf16*)alloc((long)16 * 64 * 1024 * 2);
  __bf16* ob     = (__bf16*)alloc((long)2048 * 512 * 2);
  __bf16* mid    = (__bf16*)alloc((long)2048 * 2048 * 2);
  __bf16* scores = (__bf16*)alloc((long)16 * 1024 * 1024 * 2);

  auto tconv = [&](const float* in, __bf16* o, int R, int C, int Lz,
                   long outS, long outOff) {
    transpose_cvt<<<dim3(C / 32, R / 32, Lz), 256, 0, stream>>>(
        in, o, R, C, (long)R * C, outS, outOff);
  };
  // ---- weight conversion/transpose (per launch; ws is re-poisoned) ----
  tconv(in_f[6],  encQKV, 512, 512, 6, 1536 * 512, 0);
  tconv(in_f[8],  encQKV, 512, 512, 6, 1536 * 512, 512 * 512);
  tconv(in_f[10], encQKV, 512, 512, 6, 1536 * 512, 1024 * 512);
  tconv(in_f[12], encWoT, 512, 512, 6, 512 * 512, 0);
  tconv(in_f[14], encW1T, 512, 2048, 6, (long)2048 * 512, 0);
  tconv(in_f[16], encW2T, 2048, 512, 6, (long)2048 * 512, 0);
  tconv(in_f[18], dsaQKV, 512, 512, 6, 1536 * 512, 0);
  tconv(in_f[20], dsaQKV, 512, 512, 6, 1536 * 512, 512 * 512);
  tconv(in_f[22], dsaQKV, 512, 512, 6, 1536 * 512, 1024 * 512);
  tconv(in_f[24], dsaWoT, 512, 512, 6, 512 * 512, 0);
  tconv(in_f[26], dcaQKV, 512, 512, 6, 1536 * 512, 0);
  tconv(in_f[28], dcaQKV, 512, 512, 6, 1536 * 512, 512 * 512);
  tconv(in_f[30], dcaQKV, 512, 512, 6, 1536 * 512, 1024 * 512);
  tconv(in_f[32], dcaWoT, 512, 512, 6, 512 * 512, 0);
  tconv(in_f[34], decW1T, 512, 2048, 6, (long)2048 * 512, 0);
  tconv(in_f[36], decW2T, 2048, 512, 6, (long)2048 * 512, 0);
  tconv(in_f[38], projT, 512, 32000, 1, 0, 0);

  const long sAh64 = 64, sZA = (long)1024 * 1536, sZS = (long)1024 * 1024;

  auto attn_core = [&](const int* mask, int mode, const __bf16* woT_l,
                       const float* bo_l) {
    vtrans_kernel<<<dim3(32, 2, 16), 256, 0, stream>>>(qkv, vT);
    // scores = Q K^T / 8
    gemm_bt<128, 128, 0, false, false><<<dim3(8, 8, 16), 256, 0, stream>>>(
        qkv, 1536, sZA, sAh64, qkv + 512, 1536, sZA, sAh64, scores, 1024,
        (long)8 * sZS, sZS, nullptr, nullptr, nullptr, 64, 8, 0.125f);
    if (mode == 0)
      softmax_kernel<0><<<16384, 256, 0, stream>>>(scores, mask);
    else
      softmax_kernel<1><<<16384, 256, 0, stream>>>(scores, mask);
    // O = P V   (B = vT [dh][s])
    gemm_bt<64, 64, 0, false, false><<<dim3(1, 16, 16), 256, 0, stream>>>(
        scores, 1024, (long)8 * sZS, sZS, vT, 1024, (long)8 * 64 * 1024,
        (long)64 * 1024, ob, 512, (long)1024 * 512, 64, nullptr, nullptr,
        nullptr, 1024, 8, 1.f);
    // x += O Wo + bo   (split-K 2, atomic)
    gemm_bt<64, 64, 4, false, false><<<dim3(8, 32, 2), 256, 0, stream>>>(
        ob, 512, 256, 0, woT_l, 512, 256, 0, x, 512, 0, 0, bo_l, nullptr,
        nullptr, 256, 1, 1.f);
  };

  auto ffn = [&](const __bf16* w1T_l, const float* b1_l, const __bf16* w2T_l,
                 const float* b2_l) {
    gemm_bt<128, 64, 1, false, false><<<dim3(32, 16, 1), 256, 0, stream>>>(
        h, 512, 0, 0, w1T_l, 512, 0, 0, mid, 2048, 0, 0, b1_l, nullptr,
        nullptr, 512, 1, 1.f);
    gemm_bt<64, 64, 4, false, false><<<dim3(8, 32, 2), 256, 0, stream>>>(
        mid, 2048, 1024, 0, w2T_l, 2048, 1024, 0, x, 512, 0, 0, b2_l, nullptr,
        nullptr, 1024, 1, 1.f);
  };

  const int rows = C_B * C_S;

  // ================= encoder =================
  embed_kernel<<<rows, 256, 0, stream>>>(src, src_emb, x);
  for (int i = 0; i < C_L; ++i) {
    const long oW = (long)i * 1536 * 512, oB = (long)i * 512;
    ln_kernel<<<rows, 256, 0, stream>>>(x, h);
    gemm_bt<128, 64, 0, true, false><<<dim3(24, 16, 1), 256, 0, stream>>>(
        h, 512, 0, 0, encQKV + oW, 512, 0, 0, qkv, 1536, 0, 0,
        in_f[7] + oB, in_f[9] + oB, in_f[11] + oB, 512, 1, 1.f);
    attn_core(src_mask, 0, encWoT + (long)i * 512 * 512, in_f[13] + oB);
    ln_kernel<<<rows, 256, 0, stream>>>(x, h);
    ffn(encW1T + (long)i * 2048 * 512, in_f[15] + (long)i * 2048,
        encW2T + (long)i * 2048 * 512, in_f[17] + oB);
  }
  ln_kernel<<<rows, 256, 0, stream>>>(x, encb);

  // ================= decoder =================
  embed_kernel<<<rows, 256, 0, stream>>>(tgt, tgt_emb, x);
  for (int i = 0; i < C_L; ++i) {
    const long oW = (long)i * 1536 * 512, oB = (long)i * 512;
    // self-attn (reference quirk: src_mask)
    ln_kernel<<<rows, 256, 0, stream>>>(x, h);
    gemm_bt<128, 64, 0, true, false><<<dim3(24, 16, 1), 256, 0, stream>>>(
        h, 512, 0, 0, dsaQKV + oW, 512, 0, 0, qkv, 1536, 0, 0,
        in_f[19] + oB, in_f[21] + oB, in_f[23] + oB, 512, 1, 1.f);
    attn_core(src_mask, 0, dsaWoT + (long)i * 512 * 512, in_f[25] + oB);
    // cross-attn (reference quirk: tgt_mask); Q from h, K/V from encb
    ln_kernel<<<rows, 256, 0, stream>>>(x, h);
    gemm_bt<64, 64, 0, false, false><<<dim3(8, 32, 1), 256, 0, stream>>>(
        h, 512, 0, 0, dcaQKV + oW, 512, 0, 0, qkv, 1536, 0, 0,
        in_f[27] + oB, nullptr, nullptr, 512, 1, 1.f);
    gemm_bt<128, 64, 0, true, false><<<dim3(16, 16, 1), 256, 0, stream>>>(
        encb, 512, 0, 0, dcaQKV + oW + (long)512 * 512, 512, 0, 0, qkv + 512,
        1536, 0, 0, in_f[29] + oB, in_f[31] + oB, nullptr, 512, 1, 1.f);
    attn_core(tgt_mask, 1, dcaWoT + (long)i * 512 * 512, in_f[33] + oB);
    ln_kernel<<<rows, 256, 0, stream>>>(x, h);
    ffn(decW1T + (long)i * 2048 * 512, in_f[35] + (long)i * 2048,
        decW2T + (long)i * 2048 * 512, in_f[37] + oB);
  }
  ln_kernel<<<rows, 256, 0, stream>>>(x, h);

  // ---- final projection (SWAP grid: M-major for proj_w L2 reuse) ----
  gemm_bt<128, 128, 3, false, true><<<dim3(16, 250, 1), 256, 0, stream>>>(
      h, 512, 0, 0, projT, 512, 0, 0, out, 32000, 0, 0, in_f[39], nullptr,
      nullptr, 512, 1, 1.f);
  logsoftmax_kernel<<<rows, 256, 0, stream>>>(out);
}